// Round 3
// baseline (819.609 us; speedup 1.0000x reference)
//
#include <hip/hip_runtime.h>

typedef unsigned short u16;
typedef float floatx4 __attribute__((ext_vector_type(4)));
typedef short shortx8 __attribute__((ext_vector_type(8)));

#define DIN 2048

__device__ __forceinline__ u16 f2bf(float f){
  unsigned u = __float_as_uint(f);
  u = (u + 0x7fffu + ((u>>16)&1u))>>16;
  return (u16)u;
}
__device__ __forceinline__ float sigf(float x){ return 1.f/(1.f+__expf(-x)); }
__device__ __forceinline__ float siluf(float x){ return x*sigf(x); }
__device__ __forceinline__ float softplusf(float x){ return fmaxf(x,0.f)+log1pf(__expf(-fabsf(x))); }

__device__ __forceinline__ void gld_lds16(const void* g, void* l){
  __builtin_amdgcn_global_load_lds((const __attribute__((address_space(1))) unsigned*)g,
                                   (__attribute__((address_space(3))) unsigned*)l, 16, 0, 0);
}

// ---------------- workspace layout (bytes) ----------------
#define OFF_WINP  0ull            // 4096x1024 bf16
#define OFF_WG1   8388608ull      // 1024x2048 bf16
#define OFF_WG2   12582912ull     // 2048x1024 bf16
#define OFF_WOP   16777216ull     // 1024x2048 bf16
#define OFF_XB    20971520ull     // 1024x1024 bf16
#define OFF_XIN   23068672ull     // 1024x2048 f32
#define OFF_SGATE 31457280ull     // 1024x2048 f32 silu(gate)
#define OFF_X1    39845888ull     // 512x2048 f32
#define OFF_X2    44040192ull     // 256x2048 f32
#define OFF_XC0   46137344ull     // 1024x2048 f32   (alias later: ctx bf16)
#define OFF_XC1   54525952ull     // 512x2048 f32    (alias later: t1 bf16)
#define OFF_XC2   58720256ull     // 256x2048 f32
#define OFF_DT0   60817408ull     // 1024x2048 f32   (alias later: fused f32)
#define OFF_DT1   69206016ull     // 512x2048 f32    (alias later: g3o bf16)
#define OFF_DT2   73400320ull     // 256x2048 f32
#define OFF_Y0    75497472ull     // 1024x2048 f32   (alias later: ypre f32 1024x1024)
#define OFF_Y1    83886080ull     // 512x2048 f32
#define OFF_Y2    88080384ull     // 256x2048 f32
#define OFF_P0    90177536ull     // 1024x32 f32
#define OFF_P1    90308608ull     // 512x32 f32
#define OFF_P2    90374144ull     // 256x32 f32  (end 90406912 ~ 86.2 MiB)
// aliases
#define OFF_CTXB  OFF_XC0
#define OFF_T1B   OFF_XC1
#define OFF_FUSED OFF_DT0
#define OFF_G3O   OFF_DT1
#define OFF_YPRE  OFF_Y0

// ---------------- f32 -> bf16 conversion (5 segments, 4 elems/thread) ----------------
__global__ __launch_bounds__(256) void cvt_kernel(
    const float* __restrict__ s0, u16* __restrict__ d0,   // 4194304 (in_proj_w)
    const float* __restrict__ s1, u16* __restrict__ d1,   // 2097152 (gate_w1)
    const float* __restrict__ s2, u16* __restrict__ d2,   // 2097152 (gate_w2)
    const float* __restrict__ s3, u16* __restrict__ d3,   // 2097152 (out_proj_w)
    const float* __restrict__ s4, u16* __restrict__ d4)   // 1048576 (x)
{
  int i = (blockIdx.x*256 + threadIdx.x)*4;
  const float* s; u16* d;
  if      (i <  4194304){ s=s0; d=d0; }
  else if (i <  6291456){ s=s1; d=d1; i -=  4194304; }
  else if (i <  8388608){ s=s2; d=d2; i -=  6291456; }
  else if (i < 10485760){ s=s3; d=d3; i -=  8388608; }
  else                  { s=s4; d=d4; i -= 10485760; }
  const float4 v = *(const float4*)(s + i);
  ushort4 o; o.x = f2bf(v.x); o.y = f2bf(v.y); o.z = f2bf(v.z); o.w = f2bf(v.w);
  *(ushort4*)(d + i) = o;
}

// ---------------- MFMA bt-GEMM: C[m][n] = sum_k A[m][k]*B[n][k] (A,B bf16) ----------
// MODE 0: split write: n<2048 -> f32 x_in (out_f) ; n>=2048 -> f32 silu(gate) (out_f2)
// MODE 1: bf16 silu(acc)
// MODE 2: bf16 sigmoid(acc)*aux0_f[idx]*aux1_f[idx]
// MODE 3: f32 acc + aux0_f[idx]
template<int MODE>
__global__ __launch_bounds__(256) void gemm_bt(
    const u16* __restrict__ A, const u16* __restrict__ B,
    int M, int N, int K,
    float* __restrict__ out_f, float* __restrict__ out_f2, u16* __restrict__ out_b,
    const float* __restrict__ aux0_f, const float* __restrict__ aux1_f)
{
  __shared__ u16 smA[128*32];
  __shared__ u16 smB[128*32];
  const int tid  = threadIdx.x;
  const int m0   = blockIdx.y * 128;
  const int n0   = blockIdx.x * 128;
  const int wv   = tid >> 6;
  const int lane = tid & 63;
  const int mw   = (wv >> 1) * 64;
  const int nw   = (wv & 1) * 64;
  const int quad = lane >> 4;
  const int l16  = lane & 15;
  const int srow = tid >> 2;          // 0..63
  const int scol = (tid & 3) * 8;     // bf16 elems

  floatx4 acc[4][4];
#pragma unroll
  for (int i=0;i<4;i++)
#pragma unroll
    for (int j=0;j<4;j++) acc[i][j] = (floatx4)0.f;

  for (int k0 = 0; k0 < K; k0 += 32) {
    __syncthreads();
#pragma unroll
    for (int p=0;p<2;p++){
      gld_lds16(A + (size_t)(m0 + p*64 + srow)*K + k0 + scol, &smA[p*2048 + wv*512]);
      gld_lds16(B + (size_t)(n0 + p*64 + srow)*K + k0 + scol, &smB[p*2048 + wv*512]);
    }
    __syncthreads();
    shortx8 af[4], bfr[4];
#pragma unroll
    for (int i=0;i<4;i++){
      af[i]  = *(const shortx8*)&smA[(mw + i*16 + l16)*32 + quad*8];
      bfr[i] = *(const shortx8*)&smB[(nw + i*16 + l16)*32 + quad*8];
    }
#pragma unroll
    for (int i=0;i<4;i++)
#pragma unroll
      for (int j=0;j<4;j++)
        acc[i][j] = __builtin_amdgcn_mfma_f32_16x16x32_bf16(af[i], bfr[j], acc[i][j], 0, 0, 0);
  }

#pragma unroll
  for (int i=0;i<4;i++){
#pragma unroll
    for (int r=0;r<4;r++){
      const int m = m0 + mw + i*16 + quad*4 + r;
#pragma unroll
      for (int j=0;j<4;j++){
        const int n = n0 + nw + j*16 + l16;
        const float v = acc[i][j][r];
        if (MODE == 0){
          if (n < 2048) out_f [(size_t)m*2048 + n]        = v;
          else          out_f2[(size_t)m*2048 + (n-2048)] = siluf(v);
        } else if (MODE == 1){
          out_b[(size_t)m*N + n] = f2bf(siluf(v));
        } else if (MODE == 2){
          const size_t idx = (size_t)m*N + n;
          out_b[idx] = f2bf(sigf(v) * aux0_f[idx] * aux1_f[idx]);
        } else {
          const size_t idx = (size_t)m*N + n;
          out_f[idx] = v + aux0_f[idx];
        }
      }
    }
  }
}

// ---------------- downsample: x1 (mean2), x2 (mean4) ----------------
__global__ __launch_bounds__(256) void down_kernel(const float* __restrict__ xin,
                                                   float* __restrict__ x1, float* __restrict__ x2){
  const int idx = blockIdx.x*256 + threadIdx.x;
  const int n1 = 512*DIN;
  if (idx < n1){
    const int t = idx >> 11, d = idx & 2047;
    x1[idx] = 0.5f*(xin[(size_t)(2*t)*DIN + d] + xin[(size_t)(2*t+1)*DIN + d]);
  } else {
    const int k = idx - n1;
    const int t = k >> 11, d = k & 2047;
    x2[k] = 0.25f*(xin[(size_t)(4*t)*DIN + d] + xin[(size_t)(4*t+1)*DIN + d]
                 + xin[(size_t)(4*t+2)*DIN + d] + xin[(size_t)(4*t+3)*DIN + d]);
  }
}

// ---------------- causal depthwise conv (K=4) + silu, all scales ----------------
__global__ __launch_bounds__(256) void conv_kernel(const float* __restrict__ xin,
    const float* __restrict__ x1, const float* __restrict__ x2,
    const float* __restrict__ cw, const float* __restrict__ cb,
    float* __restrict__ xc0, float* __restrict__ xc1, float* __restrict__ xc2){
  const int idx = blockIdx.x*256 + threadIdx.x;
  const float* xs; float* xc; int s, local;
  if (idx < 1024*DIN)              { s=0; local=idx;             xs=xin; xc=xc0; }
  else if (idx < (1024+512)*DIN)   { s=1; local=idx-1024*DIN;    xs=x1;  xc=xc1; }
  else                             { s=2; local=idx-1536*DIN;    xs=x2;  xc=xc2; }
  const int t = local >> 11, d = local & 2047;
  const float* w = cw + ((size_t)(s*DIN) + d)*4;
  float acc = cb[s*DIN + d];
#pragma unroll
  for (int j=0;j<4;j++){
    const int tt = t - 3 + j;
    if (tt >= 0) acc += w[j] * xs[(size_t)tt*DIN + d];
  }
  xc[local] = siluf(acc);
}

// ---------------- xproj: proj[t][i] = sum_d xc[t][d]*xw[i][d], i<32 ----------------
__global__ __launch_bounds__(256) void xproj_kernel(const float* __restrict__ xc0,
    const float* __restrict__ xc1, const float* __restrict__ xc2,
    const float* __restrict__ xw,
    float* __restrict__ p0, float* __restrict__ p1, float* __restrict__ p2){
  const int wid  = (blockIdx.x*256 + threadIdx.x) >> 6;
  const int lane = threadIdx.x & 63;
  const float* xc; float* proj; int s, local;
  if (wid < 1024*32)      { s=0; local=wid;         xc=xc0; proj=p0; }
  else if (wid < 1536*32) { s=1; local=wid-1024*32; xc=xc1; proj=p1; }
  else                    { s=2; local=wid-1536*32; xc=xc2; proj=p2; }
  const int t = local >> 5, i = local & 31;
  const float* w  = xw + ((size_t)s*32 + i)*DIN;
  const float* xr = xc + (size_t)t*DIN;
  float acc = 0.f;
#pragma unroll 4
  for (int k=lane; k<DIN; k+=64) acc += xr[k]*w[k];
  acc += __shfl_xor(acc,1);  acc += __shfl_xor(acc,2);  acc += __shfl_xor(acc,4);
  acc += __shfl_xor(acc,8);  acc += __shfl_xor(acc,16); acc += __shfl_xor(acc,32);
  if (lane == 0) proj[t*32 + i] = acc;
}

// ---------------- dtproj + double softplus ----------------
__global__ __launch_bounds__(256) void dtproj_kernel(const float* __restrict__ p0,
    const float* __restrict__ p1, const float* __restrict__ p2,
    const float* __restrict__ dtw, const float* __restrict__ dtb,
    float* __restrict__ dt0, float* __restrict__ dt1, float* __restrict__ dt2){
  const int idx = blockIdx.x*256 + threadIdx.x;
  const float* proj; float* dt; int s, local;
  if (idx < 1024*DIN)            { s=0; local=idx;          proj=p0; dt=dt0; }
  else if (idx < (1024+512)*DIN) { s=1; local=idx-1024*DIN; proj=p1; dt=dt1; }
  else                           { s=2; local=idx-1536*DIN; proj=p2; dt=dt2; }
  const int t = local >> 11, d = local & 2047;
  const float* w  = dtw + ((size_t)(s*DIN) + d)*16;
  const float* pr = proj + t*32;
  float acc = dtb[s*DIN + d];
#pragma unroll
  for (int n=0;n<16;n++) acc += pr[n]*w[n];
  dt[local] = softplusf(softplusf(acc));
}

// ---------------- SSM scan: 16 lanes per channel (one per state) ----------------
__global__ __launch_bounds__(256) void scan_kernel(
    const float* __restrict__ xc0, const float* __restrict__ xc1, const float* __restrict__ xc2,
    const float* __restrict__ p0,  const float* __restrict__ p1,  const float* __restrict__ p2,
    const float* __restrict__ dt0, const float* __restrict__ dt1, const float* __restrict__ dt2,
    const float* __restrict__ Dp_all,
    float* __restrict__ y0, float* __restrict__ y1, float* __restrict__ y2){
  const int b = blockIdx.x;
  const int s = b >> 7, bb = b & 127;
  const float *xc, *proj, *dt; float* y; int T;
  if (s == 0)      { xc=xc0; proj=p0; dt=dt0; y=y0; T=1024; }
  else if (s == 1) { xc=xc1; proj=p1; dt=dt1; y=y1; T=512;  }
  else             { xc=xc2; proj=p2; dt=dt2; y=y2; T=256;  }
  const int n = threadIdx.x & 15;
  const int d = bb*16 + (threadIdx.x >> 4);
  const float Acoef = -(float)(n+1);
  const float Dv = Dp_all[s*DIN + d];
  float H = 0.f;
#pragma unroll 4
  for (int t=0; t<T; t++){
    const float dtv = dt[(size_t)t*DIN + d];
    const float xcv = xc[(size_t)t*DIN + d];
    const float Bv  = proj[t*32 + n];
    const float Cv  = proj[t*32 + 16 + n];
    const float dA  = fmaxf(__expf(dtv*Acoef), 1e-38f);
    const float dBx = fmaxf(dtv*Bv*xcv, 1e-38f);
    H = dA*H + dBx;
    float p = Cv*H;
    p += __shfl_xor(p,1); p += __shfl_xor(p,2); p += __shfl_xor(p,4); p += __shfl_xor(p,8);
    if (n == 0) y[(size_t)t*DIN + d] = p + Dv*xcv;
  }
}

// ---------------- upsample + fuse + ctx ----------------
__device__ __forceinline__ float ups_read(const float* __restrict__ ys, int Tin, int t, int d){
  const float scale = (float)Tin * (1.f/1024.f);
  float pos = ((float)t + 0.5f)*scale - 0.5f;
  pos = fminf(fmaxf(pos, 0.f), (float)(Tin-1));
  const int lo = (int)floorf(pos);
  const float w = pos - (float)lo;
  const int hi = min(lo+1, Tin-1);
  return ys[(size_t)lo*DIN + d]*(1.f-w) + ys[(size_t)hi*DIN + d]*w;
}

__global__ __launch_bounds__(256) void fuse_kernel(const float* __restrict__ y0,
    const float* __restrict__ y1, const float* __restrict__ y2,
    const float* __restrict__ sw, u16* __restrict__ ctxb, float* __restrict__ fused){
  const int idx = blockIdx.x*256 + threadIdx.x;
  const int t = idx >> 11, d = idx & 2047;
  const float w0r = sw[0], w1r = sw[1], w2r = sw[2];
  const float mx = fmaxf(w0r, fmaxf(w1r, w2r));
  float e0 = __expf(w0r-mx), e1 = __expf(w1r-mx), e2 = __expf(w2r-mx);
  const float inv = 1.f/(e0+e1+e2);
  e0 *= inv; e1 *= inv; e2 *= inv;
  const float o0 = y0[idx];
  const float o1 = ups_read(y1, 512, t, d);
  const float o2 = ups_read(y2, 256, t, d);
  fused[idx] = e0*o0 + e1*o1 + e2*o2;
  ctxb[idx]  = f2bf((o0+o1+o2)*(1.f/3.f));
}

// ---------------- LayerNorm ----------------
__global__ __launch_bounds__(256) void ln_kernel(const float* __restrict__ ypre,
    const float* __restrict__ g, const float* __restrict__ b, float* __restrict__ out){
  __shared__ float red[4];
  const int t = blockIdx.x;
  const float* row = ypre + (size_t)t*1024;
  float v[4];
  float s = 0.f;
#pragma unroll
  for (int i=0;i<4;i++){ v[i] = row[threadIdx.x + i*256]; s += v[i]; }
  s += __shfl_xor(s,1); s += __shfl_xor(s,2); s += __shfl_xor(s,4);
  s += __shfl_xor(s,8); s += __shfl_xor(s,16); s += __shfl_xor(s,32);
  if ((threadIdx.x & 63) == 0) red[threadIdx.x>>6] = s;
  __syncthreads();
  const float mu = (red[0]+red[1]+red[2]+red[3]) * (1.f/1024.f);
  __syncthreads();
  float q = 0.f;
#pragma unroll
  for (int i=0;i<4;i++){ const float dd = v[i]-mu; q += dd*dd; }
  q += __shfl_xor(q,1); q += __shfl_xor(q,2); q += __shfl_xor(q,4);
  q += __shfl_xor(q,8); q += __shfl_xor(q,16); q += __shfl_xor(q,32);
  if ((threadIdx.x & 63) == 0) red[threadIdx.x>>6] = q;
  __syncthreads();
  const float rstd = rsqrtf((red[0]+red[1]+red[2]+red[3]) * (1.f/1024.f) + 1e-5f);
#pragma unroll
  for (int i=0;i<4;i++){
    const int c = threadIdx.x + i*256;
    out[(size_t)t*1024 + c] = (v[i]-mu)*rstd*g[c] + b[c];
  }
}

extern "C" void kernel_launch(void* const* d_in, const int* in_sizes, int n_in,
                              void* d_out, int out_size, void* d_ws, size_t ws_size,
                              hipStream_t stream) {
  const float* x     = (const float*)d_in[0];
  const float* inpw  = (const float*)d_in[1];
  const float* convw = (const float*)d_in[2];
  const float* convb = (const float*)d_in[3];
  const float* xpw   = (const float*)d_in[4];
  const float* dtw   = (const float*)d_in[5];
  const float* dtb   = (const float*)d_in[6];
  const float* Dp    = (const float*)d_in[7];
  const float* sw    = (const float*)d_in[8];
  const float* gw1   = (const float*)d_in[9];
  const float* gw2   = (const float*)d_in[10];
  const float* opw   = (const float*)d_in[11];
  const float* lng   = (const float*)d_in[12];
  const float* lnb   = (const float*)d_in[13];
  float* out = (float*)d_out;

  char* ws = (char*)d_ws;
  u16*   wInp  = (u16*)  (ws + OFF_WINP);
  u16*   wG1   = (u16*)  (ws + OFF_WG1);
  u16*   wG2   = (u16*)  (ws + OFF_WG2);
  u16*   wOp   = (u16*)  (ws + OFF_WOP);
  u16*   xb    = (u16*)  (ws + OFF_XB);
  float* xin   = (float*)(ws + OFF_XIN);
  float* sgate = (float*)(ws + OFF_SGATE);
  float* x1    = (float*)(ws + OFF_X1);
  float* x2    = (float*)(ws + OFF_X2);
  float* xc0   = (float*)(ws + OFF_XC0);
  float* xc1   = (float*)(ws + OFF_XC1);
  float* xc2   = (float*)(ws + OFF_XC2);
  float* dt0   = (float*)(ws + OFF_DT0);
  float* dt1   = (float*)(ws + OFF_DT1);
  float* dt2   = (float*)(ws + OFF_DT2);
  float* y0    = (float*)(ws + OFF_Y0);
  float* y1    = (float*)(ws + OFF_Y1);
  float* y2    = (float*)(ws + OFF_Y2);
  float* p0    = (float*)(ws + OFF_P0);
  float* p1    = (float*)(ws + OFF_P1);
  float* p2    = (float*)(ws + OFF_P2);
  u16*   ctxb  = (u16*)  (ws + OFF_CTXB);
  u16*   t1b   = (u16*)  (ws + OFF_T1B);
  float* fused = (float*)(ws + OFF_FUSED);
  u16*   g3o   = (u16*)  (ws + OFF_G3O);
  float* ypre  = (float*)(ws + OFF_YPRE);

  // convert f32 -> bf16: big GEMM weights + x   (11534336 elems / 4 per thread)
  cvt_kernel<<<11264, 256, 0, stream>>>(inpw, wInp, gw1, wG1, gw2, wG2, opw, wOp, x, xb);
  // G1: xz = x @ in_proj_w^T -> x_in (f32), silu(gate) (f32)
  gemm_bt<0><<<dim3(32, 8), 256, 0, stream>>>(xb, wInp, 1024, 4096, 1024,
                                              xin, sgate, nullptr, nullptr, nullptr);
  // downsample
  down_kernel<<<(512*DIN + 256*DIN)/256, 256, 0, stream>>>(xin, x1, x2);
  // conv + silu (all scales)
  conv_kernel<<<(1792*DIN)/256, 256, 0, stream>>>(xin, x1, x2, convw, convb, xc0, xc1, xc2);
  // xproj (all scales)
  xproj_kernel<<<(1792*32*64)/256, 256, 0, stream>>>(xc0, xc1, xc2, xpw, p0, p1, p2);
  // dtproj + softplus^2
  dtproj_kernel<<<(1792*DIN)/256, 256, 0, stream>>>(p0, p1, p2, dtw, dtb, dt0, dt1, dt2);
  // SSM scan
  scan_kernel<<<384, 256, 0, stream>>>(xc0, xc1, xc2, p0, p1, p2, dt0, dt1, dt2, Dp, y0, y1, y2);
  // upsample + fuse + ctx   (writes ctxb over xc0, fused over dt0 — both dead)
  fuse_kernel<<<(1024*DIN)/256, 256, 0, stream>>>(y0, y1, y2, sw, ctxb, fused);
  // G2: t1 = silu(ctx @ gate_w1^T)  (bf16, over xc1)
  gemm_bt<1><<<dim3(8, 8), 256, 0, stream>>>(ctxb, wG1, 1024, 1024, 2048,
                                             nullptr, nullptr, t1b, nullptr, nullptr);
  // G3: g3o = sigmoid(t1 @ gate_w2^T) * fused * sgate  (bf16, over dt1)
  gemm_bt<2><<<dim3(16, 8), 256, 0, stream>>>(t1b, wG2, 1024, 2048, 1024,
                                              nullptr, nullptr, g3o, fused, sgate);
  // G4: ypre = g3o @ out_proj_w^T + x  (f32, over y0)
  gemm_bt<3><<<dim3(8, 8), 256, 0, stream>>>(g3o, wOp, 1024, 1024, 2048,
                                             ypre, nullptr, nullptr, x, nullptr);
  // LayerNorm -> f32 out
  ln_kernel<<<1024, 256, 0, stream>>>(ypre, lng, lnb, out);
}

// Round 4
// 395.836 us; speedup vs baseline: 2.0706x; 2.0706x over previous
//
#include <hip/hip_runtime.h>

typedef unsigned short u16;
typedef float floatx4 __attribute__((ext_vector_type(4)));
typedef short shortx8 __attribute__((ext_vector_type(8)));

#define DIN 2048

__device__ __forceinline__ u16 f2bf(float f){
  unsigned u = __float_as_uint(f);
  u = (u + 0x7fffu + ((u>>16)&1u))>>16;
  return (u16)u;
}
__device__ __forceinline__ float sigf(float x){ return 1.f/(1.f+__expf(-x)); }
__device__ __forceinline__ float siluf(float x){ return x*sigf(x); }
__device__ __forceinline__ float softplusf(float x){ return fmaxf(x,0.f)+log1pf(__expf(-fabsf(x))); }

__device__ __forceinline__ void gld_lds16(const void* g, void* l){
  __builtin_amdgcn_global_load_lds((const __attribute__((address_space(1))) unsigned*)g,
                                   (__attribute__((address_space(3))) unsigned*)l, 16, 0, 0);
}

// ---------------- workspace layout (bytes) ----------------
#define OFF_WINP  0ull            // 4096x1024 bf16
#define OFF_WG1   8388608ull      // 1024x2048 bf16
#define OFF_WG2   12582912ull     // 2048x1024 bf16
#define OFF_WOP   16777216ull     // 1024x2048 bf16
#define OFF_XB    20971520ull     // 1024x1024 bf16
#define OFF_XIN   23068672ull     // 1024x2048 f32   (dead after conv -> Hinit 7.34MB)
#define OFF_SGATE 31457280ull     // 1024x2048 f32 silu(gate)
#define OFF_X1    39845888ull     // 512x2048 f32
#define OFF_X2    44040192ull     // 256x2048 f32
#define OFF_XC0   46137344ull     // 1024x2048 f32   (alias later: ctx bf16)
#define OFF_XC1   54525952ull     // 512x2048 f32    (alias later: t1 bf16)
#define OFF_XC2   58720256ull     // 256x2048 f32
#define OFF_DT0   60817408ull     // 1024x2048 f32   (alias later: fused f32)
#define OFF_DT1   69206016ull     // 512x2048 f32    (alias later: g3o bf16)
#define OFF_DT2   73400320ull     // 256x2048 f32
#define OFF_Y0    75497472ull     // 1024x2048 f32   (pre-scan: PS summaries 14.68MB) (alias later: ypre)
#define OFF_Y1    83886080ull     // 512x2048 f32
#define OFF_Y2    88080384ull     // 256x2048 f32
#define OFF_P0    90177536ull     // 1024x32 f32
#define OFF_P1    90308608ull     // 512x32 f32
#define OFF_P2    90374144ull     // 256x32 f32  (end 90406912 ~ 86.2 MiB)
// aliases
#define OFF_CTXB  OFF_XC0
#define OFF_T1B   OFF_XC1
#define OFF_FUSED OFF_DT0
#define OFF_G3O   OFF_DT1
#define OFF_YPRE  OFF_Y0
#define OFF_PS    OFF_Y0          // 56 chunks x 2048 x 16 x float2 = 14,680,064 B (== Y0+Y1+Y2)
#define OFF_HINIT OFF_XIN         // 56 x 2048 x 16 x float = 7,340,032 B

// ---------------- f32 -> bf16 conversion (5 segments, 4 elems/thread) ----------------
__global__ __launch_bounds__(256) void cvt_kernel(
    const float* __restrict__ s0, u16* __restrict__ d0,
    const float* __restrict__ s1, u16* __restrict__ d1,
    const float* __restrict__ s2, u16* __restrict__ d2,
    const float* __restrict__ s3, u16* __restrict__ d3,
    const float* __restrict__ s4, u16* __restrict__ d4)
{
  int i = (blockIdx.x*256 + threadIdx.x)*4;
  const float* s; u16* d;
  if      (i <  4194304){ s=s0; d=d0; }
  else if (i <  6291456){ s=s1; d=d1; i -=  4194304; }
  else if (i <  8388608){ s=s2; d=d2; i -=  6291456; }
  else if (i < 10485760){ s=s3; d=d3; i -=  8388608; }
  else                  { s=s4; d=d4; i -= 10485760; }
  const float4 v = *(const float4*)(s + i);
  ushort4 o; o.x = f2bf(v.x); o.y = f2bf(v.y); o.z = f2bf(v.z); o.w = f2bf(v.w);
  *(ushort4*)(d + i) = o;
}

// ---------------- MFMA bt-GEMM: C[m][n] = sum_k A[m][k]*B[n][k] (A,B bf16) ----------
// MODE 0: n<2048 -> f32 x_in (out_f) + fused downsample (ex0=x1, ex1=x2); n>=2048 -> f32 silu(gate) (out_f2)
// MODE 1: bf16 silu(acc)
// MODE 2: bf16 sigmoid(acc)*ex0[idx]*ex1[idx]
// MODE 3: f32 acc + ex0[idx]
template<int MODE>
__global__ __launch_bounds__(256) void gemm_bt(
    const u16* __restrict__ A, const u16* __restrict__ B,
    int M, int N, int K,
    float* __restrict__ out_f, float* __restrict__ out_f2, u16* __restrict__ out_b,
    float* __restrict__ ex0, float* __restrict__ ex1)
{
  __shared__ u16 smA[128*32];
  __shared__ u16 smB[128*32];
  const int tid  = threadIdx.x;
  const int m0   = blockIdx.y * 128;
  const int n0   = blockIdx.x * 128;
  const int wv   = tid >> 6;
  const int lane = tid & 63;
  const int mw   = (wv >> 1) * 64;
  const int nw   = (wv & 1) * 64;
  const int quad = lane >> 4;
  const int l16  = lane & 15;
  const int srow = tid >> 2;
  const int scol = (tid & 3) * 8;

  floatx4 acc[4][4];
#pragma unroll
  for (int i=0;i<4;i++)
#pragma unroll
    for (int j=0;j<4;j++) acc[i][j] = (floatx4)0.f;

  for (int k0 = 0; k0 < K; k0 += 32) {
    __syncthreads();
#pragma unroll
    for (int p=0;p<2;p++){
      gld_lds16(A + (size_t)(m0 + p*64 + srow)*K + k0 + scol, &smA[p*2048 + wv*512]);
      gld_lds16(B + (size_t)(n0 + p*64 + srow)*K + k0 + scol, &smB[p*2048 + wv*512]);
    }
    __syncthreads();
    shortx8 af[4], bfr[4];
#pragma unroll
    for (int i=0;i<4;i++){
      af[i]  = *(const shortx8*)&smA[(mw + i*16 + l16)*32 + quad*8];
      bfr[i] = *(const shortx8*)&smB[(nw + i*16 + l16)*32 + quad*8];
    }
#pragma unroll
    for (int i=0;i<4;i++)
#pragma unroll
      for (int j=0;j<4;j++)
        acc[i][j] = __builtin_amdgcn_mfma_f32_16x16x32_bf16(af[i], bfr[j], acc[i][j], 0, 0, 0);
  }

#pragma unroll
  for (int i=0;i<4;i++){
    const int mb = m0 + mw + i*16 + quad*4;   // 4 consecutive rows mb..mb+3 per lane
#pragma unroll
    for (int j=0;j<4;j++){
      const int n = n0 + nw + j*16 + l16;
      const floatx4 v4 = acc[i][j];
      if (MODE == 0){
        if (n < 2048){
#pragma unroll
          for (int r=0;r<4;r++) out_f[(size_t)(mb+r)*2048 + n] = v4[r];
          // fused downsample (rows mb..mb+3 are consecutive t, mb%4==0)
          ex0[(size_t)(mb>>1)*2048 + n]       = 0.5f*(v4[0]+v4[1]);
          ex0[(size_t)((mb>>1)+1)*2048 + n]   = 0.5f*(v4[2]+v4[3]);
          ex1[(size_t)(mb>>2)*2048 + n]       = 0.25f*(v4[0]+v4[1]+v4[2]+v4[3]);
        } else {
#pragma unroll
          for (int r=0;r<4;r++) out_f2[(size_t)(mb+r)*2048 + (n-2048)] = siluf(v4[r]);
        }
      } else if (MODE == 1){
#pragma unroll
        for (int r=0;r<4;r++) out_b[(size_t)(mb+r)*N + n] = f2bf(siluf(v4[r]));
      } else if (MODE == 2){
#pragma unroll
        for (int r=0;r<4;r++){
          const size_t idx = (size_t)(mb+r)*N + n;
          out_b[idx] = f2bf(sigf(v4[r]) * ex0[idx] * ex1[idx]);
        }
      } else {
#pragma unroll
        for (int r=0;r<4;r++){
          const size_t idx = (size_t)(mb+r)*N + n;
          out_f[idx] = v4[r] + ex0[idx];
        }
      }
    }
  }
}

// ---------------- causal depthwise conv (K=4) + silu, all scales ----------------
__global__ __launch_bounds__(256) void conv_kernel(const float* __restrict__ xin,
    const float* __restrict__ x1, const float* __restrict__ x2,
    const float* __restrict__ cw, const float* __restrict__ cb,
    float* __restrict__ xc0, float* __restrict__ xc1, float* __restrict__ xc2){
  const int idx = blockIdx.x*256 + threadIdx.x;
  const float* xs; float* xc; int s, local;
  if (idx < 1024*DIN)              { s=0; local=idx;             xs=xin; xc=xc0; }
  else if (idx < (1024+512)*DIN)   { s=1; local=idx-1024*DIN;    xs=x1;  xc=xc1; }
  else                             { s=2; local=idx-1536*DIN;    xs=x2;  xc=xc2; }
  const int t = local >> 11, d = local & 2047;
  const float* w = cw + ((size_t)(s*DIN) + d)*4;
  float acc = cb[s*DIN + d];
#pragma unroll
  for (int j=0;j<4;j++){
    const int tt = t - 3 + j;
    if (tt >= 0) acc += w[j] * xs[(size_t)tt*DIN + d];
  }
  xc[local] = siluf(acc);
}

// ---------------- xproj: block per t, xc row staged in LDS ----------------
// proj[t][i] = sum_k xc[t][k] * xw[s][i][k],  i<32
__global__ __launch_bounds__(256) void xproj_kernel(const float* __restrict__ xc0,
    const float* __restrict__ xc1, const float* __restrict__ xc2,
    const float* __restrict__ xw,
    float* __restrict__ p0, float* __restrict__ p1, float* __restrict__ p2){
  __shared__ float srow[DIN];
  const int b = blockIdx.x;
  const float* xc; float* proj; int s, t;
  if (b < 1024)      { s=0; t=b;       xc=xc0; proj=p0; }
  else if (b < 1536) { s=1; t=b-1024;  xc=xc1; proj=p1; }
  else               { s=2; t=b-1536;  xc=xc2; proj=p2; }
  const float* xr = xc + (size_t)t*DIN;
  const int tid = threadIdx.x;
#pragma unroll
  for (int q=0;q<2;q++){
    const int k = (q*256 + tid)*4;
    *(float4*)&srow[k] = *(const float4*)&xr[k];
  }
  __syncthreads();
  const int i = tid >> 3;        // 0..31
  const int j = tid & 7;         // 0..7
  const float* w = xw + ((size_t)s*32 + i)*DIN;
  float acc = 0.f;
#pragma unroll 8
  for (int c=0;c<256;c++){
    const int k = j + 8*c;       // stride-8 interleave: conflict-free LDS
    acc += srow[k]*w[k];
  }
  acc += __shfl_xor(acc,1); acc += __shfl_xor(acc,2); acc += __shfl_xor(acc,4);
  if (j == 0) proj[t*32 + i] = acc;
}

// ---------------- dtproj + double softplus ----------------
__global__ __launch_bounds__(256) void dtproj_kernel(const float* __restrict__ p0,
    const float* __restrict__ p1, const float* __restrict__ p2,
    const float* __restrict__ dtw, const float* __restrict__ dtb,
    float* __restrict__ dt0, float* __restrict__ dt1, float* __restrict__ dt2){
  const int idx = blockIdx.x*256 + threadIdx.x;
  const float* proj; float* dt; int s, local;
  if (idx < 1024*DIN)            { s=0; local=idx;          proj=p0; dt=dt0; }
  else if (idx < (1024+512)*DIN) { s=1; local=idx-1024*DIN; proj=p1; dt=dt1; }
  else                           { s=2; local=idx-1536*DIN; proj=p2; dt=dt2; }
  const int t = local >> 11, d = local & 2047;
  const float* w  = dtw + ((size_t)(s*DIN) + d)*16;
  const float* pr = proj + t*32;
  float acc = dtb[s*DIN + d];
#pragma unroll
  for (int n=0;n<16;n++) acc += pr[n]*w[n];
  dt[local] = softplusf(softplusf(acc));
}

// ---------------- chunked scan, phase 1: per-chunk local scan from H=0 ----------------
// L=32. blocks: s0: 8 dblk x 32 chunks = 256; s1: 8x16=128; s2: 8x8=64. total 448.
// PS[((base+chunk)*2048 + d)*16 + n] = {P = prod dA, S = local H end}
__global__ __launch_bounds__(256) void scan_p1(
    const float* __restrict__ xc0, const float* __restrict__ xc1, const float* __restrict__ xc2,
    const float* __restrict__ p0,  const float* __restrict__ p1,  const float* __restrict__ p2,
    const float* __restrict__ dt0, const float* __restrict__ dt1, const float* __restrict__ dt2,
    float2* __restrict__ PS)
{
  __shared__ float sproj[32*32];
  int b = blockIdx.x;
  const float *xc, *proj, *dt; int base;
  if (b < 256)      { xc=xc0; proj=p0; dt=dt0; base=0; }
  else if (b < 384) { b-=256; xc=xc1; proj=p1; dt=dt1; base=32; }
  else              { b-=384; xc=xc2; proj=p2; dt=dt2; base=48; }
  const int chunk = b >> 3;
  const int d     = (b & 7)*256 + threadIdx.x;
  const int t0    = chunk*32;
  {
    const int k = threadIdx.x*4;
    *(float4*)&sproj[k] = *(const float4*)&proj[t0*32 + k];
  }
  __syncthreads();

  float H[16], P[16];
#pragma unroll
  for (int n=0;n<16;n++){ H[n]=0.f; P[n]=1.f; }
  const float* dtp = dt + (size_t)t0*DIN + d;
  const float* xcp = xc + (size_t)t0*DIN + d;
  float dtn = dtp[0], xcn = xcp[0];
  for (int tt=0; tt<32; tt++){
    const float dtv = dtn, xcv = xcn;
    if (tt < 31){ dtn = dtp[(size_t)(tt+1)*DIN]; xcn = xcp[(size_t)(tt+1)*DIN]; }
    const float e = __expf(-dtv);          // dt >= ln2 -> e <= 0.5
    const float c = dtv*xcv;
    const float* Bp = &sproj[tt*32];
    float ep = e;
#pragma unroll
    for (int n=0;n<16;n++){
      const float dA  = fmaxf(ep, 1e-38f);
      const float dBx = fmaxf(c*Bp[n], 1e-38f);
      H[n] = dA*H[n] + dBx;
      P[n] *= dA;
      ep *= e;
    }
  }
  float2* o = PS + ((size_t)(base+chunk)*2048 + d)*16;
#pragma unroll
  for (int n=0;n<16;n++){ float2 v; v.x=P[n]; v.y=H[n]; o[n]=v; }
}

// ---------------- combine: sequential scan over chunk summaries per (s,d,n) ----------
__global__ __launch_bounds__(256) void scan_combine(const float2* __restrict__ PS,
                                                    float* __restrict__ Hinit){
  int id = blockIdx.x*256 + threadIdx.x;      // 98304
  int base, C;
  if (id < 32768)      { base=0;  C=32; }
  else if (id < 65536) { id-=32768; base=32; C=16; }
  else                 { id-=65536; base=48; C=8;  }
  const size_t off = (size_t)base*32768 + id;   // ((base+c)*2048+d)*16+n with id=d*16+n
  const float2* ps = PS + off;
  float* hi = Hinit + off;
  float H = 0.f;
  for (int c=0;c<C;c++){
    hi[(size_t)c*32768] = H;
    const float2 v = ps[(size_t)c*32768];
    H = v.x*H + v.y;
  }
}

// ---------------- chunked scan, phase 2: replay with correct H_init, emit y -----------
__global__ __launch_bounds__(256) void scan_p2(
    const float* __restrict__ xc0, const float* __restrict__ xc1, const float* __restrict__ xc2,
    const float* __restrict__ p0,  const float* __restrict__ p1,  const float* __restrict__ p2,
    const float* __restrict__ dt0, const float* __restrict__ dt1, const float* __restrict__ dt2,
    const float* __restrict__ Hinit, const float* __restrict__ Dp_all,
    float* __restrict__ y0, float* __restrict__ y1, float* __restrict__ y2)
{
  __shared__ float sproj[32*32];
  int b = blockIdx.x;
  const float *xc, *proj, *dt; float* y; int base, s;
  if (b < 256)      { xc=xc0; proj=p0; dt=dt0; y=y0; base=0;  s=0; }
  else if (b < 384) { b-=256; xc=xc1; proj=p1; dt=dt1; y=y1; base=32; s=1; }
  else              { b-=384; xc=xc2; proj=p2; dt=dt2; y=y2; base=48; s=2; }
  const int chunk = b >> 3;
  const int d     = (b & 7)*256 + threadIdx.x;
  const int t0    = chunk*32;
  {
    const int k = threadIdx.x*4;
    *(float4*)&sproj[k] = *(const float4*)&proj[t0*32 + k];
  }
  __syncthreads();

  float H[16];
  const float* hi = Hinit + ((size_t)(base+chunk)*2048 + d)*16;
#pragma unroll
  for (int n=0;n<16;n++) H[n] = hi[n];
  const float Dv = Dp_all[s*DIN + d];
  const float* dtp = dt + (size_t)t0*DIN + d;
  const float* xcp = xc + (size_t)t0*DIN + d;
  float* yp = y + (size_t)t0*DIN + d;
  float dtn = dtp[0], xcn = xcp[0];
  for (int tt=0; tt<32; tt++){
    const float dtv = dtn, xcv = xcn;
    if (tt < 31){ dtn = dtp[(size_t)(tt+1)*DIN]; xcn = xcp[(size_t)(tt+1)*DIN]; }
    const float e = __expf(-dtv);
    const float c = dtv*xcv;
    const float* Bp = &sproj[tt*32];
    float ep = e;
    float pacc = 0.f;
#pragma unroll
    for (int n=0;n<16;n++){
      const float dA  = fmaxf(ep, 1e-38f);
      const float dBx = fmaxf(c*Bp[n], 1e-38f);
      H[n] = dA*H[n] + dBx;
      pacc += Bp[16+n]*H[n];
      ep *= e;
    }
    yp[(size_t)tt*DIN] = pacc + Dv*xcv;
  }
}

// ---------------- upsample + fuse + ctx ----------------
__device__ __forceinline__ float ups_read(const float* __restrict__ ys, int Tin, int t, int d){
  const float scale = (float)Tin * (1.f/1024.f);
  float pos = ((float)t + 0.5f)*scale - 0.5f;
  pos = fminf(fmaxf(pos, 0.f), (float)(Tin-1));
  const int lo = (int)floorf(pos);
  const float w = pos - (float)lo;
  const int hi = min(lo+1, Tin-1);
  return ys[(size_t)lo*DIN + d]*(1.f-w) + ys[(size_t)hi*DIN + d]*w;
}

__global__ __launch_bounds__(256) void fuse_kernel(const float* __restrict__ y0,
    const float* __restrict__ y1, const float* __restrict__ y2,
    const float* __restrict__ sw, u16* __restrict__ ctxb, float* __restrict__ fused){
  const int idx = blockIdx.x*256 + threadIdx.x;
  const int t = idx >> 11, d = idx & 2047;
  const float w0r = sw[0], w1r = sw[1], w2r = sw[2];
  const float mx = fmaxf(w0r, fmaxf(w1r, w2r));
  float e0 = __expf(w0r-mx), e1 = __expf(w1r-mx), e2 = __expf(w2r-mx);
  const float inv = 1.f/(e0+e1+e2);
  e0 *= inv; e1 *= inv; e2 *= inv;
  const float o0 = y0[idx];
  const float o1 = ups_read(y1, 512, t, d);
  const float o2 = ups_read(y2, 256, t, d);
  fused[idx] = e0*o0 + e1*o1 + e2*o2;
  ctxb[idx]  = f2bf((o0+o1+o2)*(1.f/3.f));
}

// ---------------- LayerNorm ----------------
__global__ __launch_bounds__(256) void ln_kernel(const float* __restrict__ ypre,
    const float* __restrict__ g, const float* __restrict__ b, float* __restrict__ out){
  __shared__ float red[4];
  const int t = blockIdx.x;
  const float* row = ypre + (size_t)t*1024;
  float v[4];
  float s = 0.f;
#pragma unroll
  for (int i=0;i<4;i++){ v[i] = row[threadIdx.x + i*256]; s += v[i]; }
  s += __shfl_xor(s,1); s += __shfl_xor(s,2); s += __shfl_xor(s,4);
  s += __shfl_xor(s,8); s += __shfl_xor(s,16); s += __shfl_xor(s,32);
  if ((threadIdx.x & 63) == 0) red[threadIdx.x>>6] = s;
  __syncthreads();
  const float mu = (red[0]+red[1]+red[2]+red[3]) * (1.f/1024.f);
  __syncthreads();
  float q = 0.f;
#pragma unroll
  for (int i=0;i<4;i++){ const float dd = v[i]-mu; q += dd*dd; }
  q += __shfl_xor(q,1); q += __shfl_xor(q,2); q += __shfl_xor(q,4);
  q += __shfl_xor(q,8); q += __shfl_xor(q,16); q += __shfl_xor(q,32);
  if ((threadIdx.x & 63) == 0) red[threadIdx.x>>6] = q;
  __syncthreads();
  const float rstd = rsqrtf((red[0]+red[1]+red[2]+red[3]) * (1.f/1024.f) + 1e-5f);
#pragma unroll
  for (int i=0;i<4;i++){
    const int c = threadIdx.x + i*256;
    out[(size_t)t*1024 + c] = (v[i]-mu)*rstd*g[c] + b[c];
  }
}

extern "C" void kernel_launch(void* const* d_in, const int* in_sizes, int n_in,
                              void* d_out, int out_size, void* d_ws, size_t ws_size,
                              hipStream_t stream) {
  const float* x     = (const float*)d_in[0];
  const float* inpw  = (const float*)d_in[1];
  const float* convw = (const float*)d_in[2];
  const float* convb = (const float*)d_in[3];
  const float* xpw   = (const float*)d_in[4];
  const float* dtw   = (const float*)d_in[5];
  const float* dtb   = (const float*)d_in[6];
  const float* Dp    = (const float*)d_in[7];
  const float* sw    = (const float*)d_in[8];
  const float* gw1   = (const float*)d_in[9];
  const float* gw2   = (const float*)d_in[10];
  const float* opw   = (const float*)d_in[11];
  const float* lng   = (const float*)d_in[12];
  const float* lnb   = (const float*)d_in[13];
  float* out = (float*)d_out;

  char* ws = (char*)d_ws;
  u16*    wInp  = (u16*)   (ws + OFF_WINP);
  u16*    wG1   = (u16*)   (ws + OFF_WG1);
  u16*    wG2   = (u16*)   (ws + OFF_WG2);
  u16*    wOp   = (u16*)   (ws + OFF_WOP);
  u16*    xb    = (u16*)   (ws + OFF_XB);
  float*  xin   = (float*) (ws + OFF_XIN);
  float*  sgate = (float*) (ws + OFF_SGATE);
  float*  x1    = (float*) (ws + OFF_X1);
  float*  x2    = (float*) (ws + OFF_X2);
  float*  xc0   = (float*) (ws + OFF_XC0);
  float*  xc1   = (float*) (ws + OFF_XC1);
  float*  xc2   = (float*) (ws + OFF_XC2);
  float*  dt0   = (float*) (ws + OFF_DT0);
  float*  dt1   = (float*) (ws + OFF_DT1);
  float*  dt2   = (float*) (ws + OFF_DT2);
  float*  y0    = (float*) (ws + OFF_Y0);
  float*  y1    = (float*) (ws + OFF_Y1);
  float*  y2    = (float*) (ws + OFF_Y2);
  float*  p0    = (float*) (ws + OFF_P0);
  float*  p1    = (float*) (ws + OFF_P1);
  float*  p2    = (float*) (ws + OFF_P2);
  float2* PS    = (float2*)(ws + OFF_PS);
  float*  Hinit = (float*) (ws + OFF_HINIT);
  u16*    ctxb  = (u16*)   (ws + OFF_CTXB);
  u16*    t1b   = (u16*)   (ws + OFF_T1B);
  float*  fused = (float*) (ws + OFF_FUSED);
  u16*    g3o   = (u16*)   (ws + OFF_G3O);
  float*  ypre  = (float*) (ws + OFF_YPRE);

  // convert f32 -> bf16: big GEMM weights + x
  cvt_kernel<<<11264, 256, 0, stream>>>(inpw, wInp, gw1, wG1, gw2, wG2, opw, wOp, x, xb);
  // G1: xz = x @ in_proj_w^T -> x_in (f32) + downsampled x1,x2 + silu(gate) (f32)
  gemm_bt<0><<<dim3(32, 8), 256, 0, stream>>>(xb, wInp, 1024, 4096, 1024,
                                              xin, sgate, nullptr, x1, x2);
  // conv + silu (all scales)
  conv_kernel<<<(1792*DIN)/256, 256, 0, stream>>>(xin, x1, x2, convw, convb, xc0, xc1, xc2);
  // xproj (block per t, LDS-staged xc row)
  xproj_kernel<<<1792, 256, 0, stream>>>(xc0, xc1, xc2, xpw, p0, p1, p2);
  // dtproj + softplus^2
  dtproj_kernel<<<(1792*DIN)/256, 256, 0, stream>>>(p0, p1, p2, dtw, dtb, dt0, dt1, dt2);
  // chunked SSM scan: local scans -> combine -> replay  (PS lives in Y0..Y2, Hinit in XIN)
  scan_p1<<<448, 256, 0, stream>>>(xc0, xc1, xc2, p0, p1, p2, dt0, dt1, dt2, PS);
  scan_combine<<<384, 256, 0, stream>>>(PS, Hinit);
  scan_p2<<<448, 256, 0, stream>>>(xc0, xc1, xc2, p0, p1, p2, dt0, dt1, dt2,
                                   Hinit, Dp, y0, y1, y2);
  // upsample + fuse + ctx
  fuse_kernel<<<(1024*DIN)/256, 256, 0, stream>>>(y0, y1, y2, sw, ctxb, fused);
  // G2: t1 = silu(ctx @ gate_w1^T)
  gemm_bt<1><<<dim3(8, 8), 256, 0, stream>>>(ctxb, wG1, 1024, 1024, 2048,
                                             nullptr, nullptr, t1b, nullptr, nullptr);
  // G3: g3o = sigmoid(t1 @ gate_w2^T) * fused * sgate
  gemm_bt<2><<<dim3(16, 8), 256, 0, stream>>>(t1b, wG2, 1024, 2048, 1024,
                                              nullptr, nullptr, g3o, fused, sgate);
  // G4: ypre = g3o @ out_proj_w^T + x
  gemm_bt<3><<<dim3(8, 8), 256, 0, stream>>>(g3o, wOp, 1024, 1024, 2048,
                                             ypre, nullptr, nullptr, const_cast<float*>(x), nullptr);
  // LayerNorm -> f32 out
  ln_kernel<<<1024, 256, 0, stream>>>(ypre, lng, lnb, out);
}

// Round 5
// 340.874 us; speedup vs baseline: 2.4044x; 1.1612x over previous
//
#include <hip/hip_runtime.h>

typedef unsigned short u16;
typedef float floatx4 __attribute__((ext_vector_type(4)));
typedef short shortx8 __attribute__((ext_vector_type(8)));

#define DIN 2048

__device__ __forceinline__ u16 f2bf(float f){
  unsigned u = __float_as_uint(f);
  u = (u + 0x7fffu + ((u>>16)&1u))>>16;
  return (u16)u;
}
__device__ __forceinline__ float sigf(float x){ return 1.f/(1.f+__expf(-x)); }
__device__ __forceinline__ float siluf(float x){ return x*sigf(x); }
__device__ __forceinline__ float softplusf(float x){ return fmaxf(x,0.f)+log1pf(__expf(-fabsf(x))); }

__device__ __forceinline__ void gld_lds16(const void* g, void* l){
  __builtin_amdgcn_global_load_lds((const __attribute__((address_space(1))) unsigned*)g,
                                   (__attribute__((address_space(3))) unsigned*)l, 16, 0, 0);
}

// ---------------- workspace layout (bytes) ----------------
#define OFF_WINP  0ull            // 4096x1024 bf16
#define OFF_WG1   8388608ull      // 1024x2048 bf16
#define OFF_WG2   12582912ull     // 2048x1024 bf16
#define OFF_WOP   16777216ull     // 1024x2048 bf16
#define OFF_XB    20971520ull     // 1024x1024 bf16
#define OFF_XIN   23068672ull     // 1024x2048 f32   (dead after conv -> Hinit 7.34MB)
#define OFF_SGATE 31457280ull     // 1024x2048 f32 silu(gate)
#define OFF_X1    39845888ull     // 512x2048 f32
#define OFF_X2    44040192ull     // 256x2048 f32
#define OFF_XC0   46137344ull     // 1024x2048 f32   (alias later: ctx bf16)
#define OFF_XC1   54525952ull     // 512x2048 f32    (alias later: t1 bf16)
#define OFF_XC2   58720256ull     // 256x2048 f32
#define OFF_DT0   60817408ull     // 1024x2048 f32   (alias later: fused f32)
#define OFF_DT1   69206016ull     // 512x2048 f32    (alias later: g3o bf16)
#define OFF_DT2   73400320ull     // 256x2048 f32
#define OFF_Y0    75497472ull     // 1024x2048 f32   (pre-scan: PS summaries) (alias later: ypre)
#define OFF_Y1    83886080ull     // 512x2048 f32
#define OFF_Y2    88080384ull     // 256x2048 f32
#define OFF_P0    90177536ull     // 1024x32 f32
#define OFF_P1    90308608ull     // 512x32 f32
#define OFF_P2    90374144ull     // 256x32 f32  (end 90406912 ~ 86.2 MiB)
// aliases
#define OFF_CTXB  OFF_XC0
#define OFF_T1B   OFF_XC1
#define OFF_FUSED OFF_DT0
#define OFF_G3O   OFF_DT1
#define OFF_YPRE  OFF_Y0
#define OFF_PS    OFF_Y0          // 56 chunks x 2048 x 16 x float2
#define OFF_HINIT OFF_XIN         // 56 x 2048 x 16 x float

// ---------------- f32 -> bf16 conversion (5 segments, 4 elems/thread) ----------------
__global__ __launch_bounds__(256) void cvt_kernel(
    const float* __restrict__ s0, u16* __restrict__ d0,
    const float* __restrict__ s1, u16* __restrict__ d1,
    const float* __restrict__ s2, u16* __restrict__ d2,
    const float* __restrict__ s3, u16* __restrict__ d3,
    const float* __restrict__ s4, u16* __restrict__ d4)
{
  int i = (blockIdx.x*256 + threadIdx.x)*4;
  const float* s; u16* d;
  if      (i <  4194304){ s=s0; d=d0; }
  else if (i <  6291456){ s=s1; d=d1; i -=  4194304; }
  else if (i <  8388608){ s=s2; d=d2; i -=  6291456; }
  else if (i < 10485760){ s=s3; d=d3; i -=  8388608; }
  else                  { s=s4; d=d4; i -= 10485760; }
  const float4 v = *(const float4*)(s + i);
  ushort4 o; o.x = f2bf(v.x); o.y = f2bf(v.y); o.z = f2bf(v.z); o.w = f2bf(v.w);
  *(ushort4*)(d + i) = o;
}

// ---------------- MFMA bt-GEMM, double-buffered, tile BMxBM, BK=32 ----------------
// C[m][n] = sum_k A[m][k]*B[n][k] (A,B bf16)
// MODE 0 (BM=128 only): n<2048 -> f32 x_in + fused downsample (ex0=x1, ex1=x2);
//                       n>=2048 -> f32 silu(gate) (out_f2)
// MODE 1: bf16 silu(acc)
// MODE 2: bf16 sigmoid(acc)*ex0[idx]*ex1[idx]
// MODE 3: f32 acc + ex0[idx]
template<int MODE, int BM>
__global__ __launch_bounds__(256) void gemm_bt(
    const u16* __restrict__ A, const u16* __restrict__ B,
    int M, int N, int K,
    float* __restrict__ out_f, float* __restrict__ out_f2, u16* __restrict__ out_b,
    float* __restrict__ ex0, float* __restrict__ ex1)
{
  constexpr int NI = BM/32;        // 16x16 tiles per wave dim (4 for 128, 2 for 64)
  constexpr int IP = BM/64;        // gld_lds16 issues per matrix per thread
  __shared__ u16 smA[2][BM*32];
  __shared__ u16 smB[2][BM*32];
  const int tid  = threadIdx.x;
  const int m0   = blockIdx.y * BM;
  const int n0   = blockIdx.x * BM;
  const int wv   = tid >> 6;
  const int lane = tid & 63;
  const int mw   = (wv >> 1) * (BM/2);
  const int nw   = (wv & 1) * (BM/2);
  const int quad = lane >> 4;
  const int l16  = lane & 15;
  const int srow = tid >> 2;
  const int scol = (tid & 3) * 8;

  floatx4 acc[NI][NI];
#pragma unroll
  for (int i=0;i<NI;i++)
#pragma unroll
    for (int j=0;j<NI;j++) acc[i][j] = (floatx4)0.f;

  auto stage = [&](int buf, int k0){
#pragma unroll
    for (int p=0;p<IP;p++){
      gld_lds16(A + (size_t)(m0 + p*64 + srow)*K + k0 + scol, &smA[buf][p*2048 + wv*512]);
      gld_lds16(B + (size_t)(n0 + p*64 + srow)*K + k0 + scol, &smB[buf][p*2048 + wv*512]);
    }
  };

  stage(0, 0);
  int cur = 0;
  for (int k0 = 0; k0 < K; k0 += 32) {
    __syncthreads();                       // staging of cur done; prev reads of cur^1 done
    if (k0 + 32 < K) stage(cur^1, k0+32);  // prefetch overlaps compute below
    shortx8 af[NI], bfr[NI];
#pragma unroll
    for (int i=0;i<NI;i++){
      af[i]  = *(const shortx8*)&smA[cur][(mw + i*16 + l16)*32 + quad*8];
      bfr[i] = *(const shortx8*)&smB[cur][(nw + i*16 + l16)*32 + quad*8];
    }
#pragma unroll
    for (int i=0;i<NI;i++)
#pragma unroll
      for (int j=0;j<NI;j++)
        acc[i][j] = __builtin_amdgcn_mfma_f32_16x16x32_bf16(af[i], bfr[j], acc[i][j], 0, 0, 0);
    cur ^= 1;
  }

#pragma unroll
  for (int i=0;i<NI;i++){
    const int mb = m0 + mw + i*16 + quad*4;   // 4 consecutive rows per lane, mb%4==0
#pragma unroll
    for (int j=0;j<NI;j++){
      const int n = n0 + nw + j*16 + l16;
      const floatx4 v4 = acc[i][j];
      if (MODE == 0){
        if (n < 2048){
#pragma unroll
          for (int r=0;r<4;r++) out_f[(size_t)(mb+r)*2048 + n] = v4[r];
          ex0[(size_t)(mb>>1)*2048 + n]       = 0.5f*(v4[0]+v4[1]);
          ex0[(size_t)((mb>>1)+1)*2048 + n]   = 0.5f*(v4[2]+v4[3]);
          ex1[(size_t)(mb>>2)*2048 + n]       = 0.25f*(v4[0]+v4[1]+v4[2]+v4[3]);
        } else {
#pragma unroll
          for (int r=0;r<4;r++) out_f2[(size_t)(mb+r)*2048 + (n-2048)] = siluf(v4[r]);
        }
      } else if (MODE == 1){
#pragma unroll
        for (int r=0;r<4;r++) out_b[(size_t)(mb+r)*N + n] = f2bf(siluf(v4[r]));
      } else if (MODE == 2){
#pragma unroll
        for (int r=0;r<4;r++){
          const size_t idx = (size_t)(mb+r)*N + n;
          out_b[idx] = f2bf(sigf(v4[r]) * ex0[idx] * ex1[idx]);
        }
      } else {
#pragma unroll
        for (int r=0;r<4;r++){
          const size_t idx = (size_t)(mb+r)*N + n;
          out_f[idx] = v4[r] + ex0[idx];
        }
      }
    }
  }
}

// ---------------- causal depthwise conv (K=4) + silu, all scales ----------------
__global__ __launch_bounds__(256) void conv_kernel(const float* __restrict__ xin,
    const float* __restrict__ x1, const float* __restrict__ x2,
    const float* __restrict__ cw, const float* __restrict__ cb,
    float* __restrict__ xc0, float* __restrict__ xc1, float* __restrict__ xc2){
  const int idx = blockIdx.x*256 + threadIdx.x;
  const float* xs; float* xc; int s, local;
  if (idx < 1024*DIN)              { s=0; local=idx;             xs=xin; xc=xc0; }
  else if (idx < (1024+512)*DIN)   { s=1; local=idx-1024*DIN;    xs=x1;  xc=xc1; }
  else                             { s=2; local=idx-1536*DIN;    xs=x2;  xc=xc2; }
  const int t = local >> 11, d = local & 2047;
  const float* w = cw + ((size_t)(s*DIN) + d)*4;
  float acc = cb[s*DIN + d];
#pragma unroll
  for (int j=0;j<4;j++){
    const int tt = t - 3 + j;
    if (tt >= 0) acc += w[j] * xs[(size_t)tt*DIN + d];
  }
  xc[local] = siluf(acc);
}

// ---------------- xproj: block per t, xc row staged in LDS ----------------
__global__ __launch_bounds__(256) void xproj_kernel(const float* __restrict__ xc0,
    const float* __restrict__ xc1, const float* __restrict__ xc2,
    const float* __restrict__ xw,
    float* __restrict__ p0, float* __restrict__ p1, float* __restrict__ p2){
  __shared__ float srow[DIN];
  const int b = blockIdx.x;
  const float* xc; float* proj; int s, t;
  if (b < 1024)      { s=0; t=b;       xc=xc0; proj=p0; }
  else if (b < 1536) { s=1; t=b-1024;  xc=xc1; proj=p1; }
  else               { s=2; t=b-1536;  xc=xc2; proj=p2; }
  const float* xr = xc + (size_t)t*DIN;
  const int tid = threadIdx.x;
#pragma unroll
  for (int q=0;q<2;q++){
    const int k = (q*256 + tid)*4;
    *(float4*)&srow[k] = *(const float4*)&xr[k];
  }
  __syncthreads();
  const int i = tid >> 3;
  const int j = tid & 7;
  const float* w = xw + ((size_t)s*32 + i)*DIN;
  float acc = 0.f;
#pragma unroll 8
  for (int c=0;c<256;c++){
    const int k = j + 8*c;
    acc += srow[k]*w[k];
  }
  acc += __shfl_xor(acc,1); acc += __shfl_xor(acc,2); acc += __shfl_xor(acc,4);
  if (j == 0) proj[t*32 + i] = acc;
}

// ---------------- dtproj + double softplus ----------------
__global__ __launch_bounds__(256) void dtproj_kernel(const float* __restrict__ p0,
    const float* __restrict__ p1, const float* __restrict__ p2,
    const float* __restrict__ dtw, const float* __restrict__ dtb,
    float* __restrict__ dt0, float* __restrict__ dt1, float* __restrict__ dt2){
  const int idx = blockIdx.x*256 + threadIdx.x;
  const float* proj; float* dt; int s, local;
  if (idx < 1024*DIN)            { s=0; local=idx;          proj=p0; dt=dt0; }
  else if (idx < (1024+512)*DIN) { s=1; local=idx-1024*DIN; proj=p1; dt=dt1; }
  else                           { s=2; local=idx-1536*DIN; proj=p2; dt=dt2; }
  const int t = local >> 11, d = local & 2047;
  const float* w  = dtw + ((size_t)(s*DIN) + d)*16;
  const float* pr = proj + t*32;
  float acc = dtb[s*DIN + d];
#pragma unroll
  for (int n=0;n<16;n++) acc += pr[n]*w[n];
  dt[local] = softplusf(softplusf(acc));
}

// ---------------- chunked scan, phase 1 ----------------
__global__ __launch_bounds__(256) void scan_p1(
    const float* __restrict__ xc0, const float* __restrict__ xc1, const float* __restrict__ xc2,
    const float* __restrict__ p0,  const float* __restrict__ p1,  const float* __restrict__ p2,
    const float* __restrict__ dt0, const float* __restrict__ dt1, const float* __restrict__ dt2,
    float2* __restrict__ PS)
{
  __shared__ float sproj[32*32];
  int b = blockIdx.x;
  const float *xc, *proj, *dt; int base;
  if (b < 256)      { xc=xc0; proj=p0; dt=dt0; base=0; }
  else if (b < 384) { b-=256; xc=xc1; proj=p1; dt=dt1; base=32; }
  else              { b-=384; xc=xc2; proj=p2; dt=dt2; base=48; }
  const int chunk = b >> 3;
  const int d     = (b & 7)*256 + threadIdx.x;
  const int t0    = chunk*32;
  {
    const int k = threadIdx.x*4;
    *(float4*)&sproj[k] = *(const float4*)&proj[t0*32 + k];
  }
  __syncthreads();

  float H[16], P[16];
#pragma unroll
  for (int n=0;n<16;n++){ H[n]=0.f; P[n]=1.f; }
  const float* dtp = dt + (size_t)t0*DIN + d;
  const float* xcp = xc + (size_t)t0*DIN + d;
  float dtn = dtp[0], xcn = xcp[0];
  for (int tt=0; tt<32; tt++){
    const float dtv = dtn, xcv = xcn;
    if (tt < 31){ dtn = dtp[(size_t)(tt+1)*DIN]; xcn = xcp[(size_t)(tt+1)*DIN]; }
    const float e = __expf(-dtv);
    const float c = dtv*xcv;
    const float* Bp = &sproj[tt*32];
    float ep = e;
#pragma unroll
    for (int n=0;n<16;n++){
      const float dA  = fmaxf(ep, 1e-38f);
      const float dBx = fmaxf(c*Bp[n], 1e-38f);
      H[n] = dA*H[n] + dBx;
      P[n] *= dA;
      ep *= e;
    }
  }
  float2* o = PS + ((size_t)(base+chunk)*2048 + d)*16;
#pragma unroll
  for (int n=0;n<16;n++){ float2 v; v.x=P[n]; v.y=H[n]; o[n]=v; }
}

// ---------------- combine ----------------
__global__ __launch_bounds__(256) void scan_combine(const float2* __restrict__ PS,
                                                    float* __restrict__ Hinit){
  int id = blockIdx.x*256 + threadIdx.x;
  int base, C;
  if (id < 32768)      { base=0;  C=32; }
  else if (id < 65536) { id-=32768; base=32; C=16; }
  else                 { id-=65536; base=48; C=8;  }
  const size_t off = (size_t)base*32768 + id;
  const float2* ps = PS + off;
  float* hi = Hinit + off;
  float H = 0.f;
  for (int c=0;c<C;c++){
    hi[(size_t)c*32768] = H;
    const float2 v = ps[(size_t)c*32768];
    H = v.x*H + v.y;
  }
}

// ---------------- chunked scan, phase 2 ----------------
__global__ __launch_bounds__(256) void scan_p2(
    const float* __restrict__ xc0, const float* __restrict__ xc1, const float* __restrict__ xc2,
    const float* __restrict__ p0,  const float* __restrict__ p1,  const float* __restrict__ p2,
    const float* __restrict__ dt0, const float* __restrict__ dt1, const float* __restrict__ dt2,
    const float* __restrict__ Hinit, const float* __restrict__ Dp_all,
    float* __restrict__ y0, float* __restrict__ y1, float* __restrict__ y2)
{
  __shared__ float sproj[32*32];
  int b = blockIdx.x;
  const float *xc, *proj, *dt; float* y; int base, s;
  if (b < 256)      { xc=xc0; proj=p0; dt=dt0; y=y0; base=0;  s=0; }
  else if (b < 384) { b-=256; xc=xc1; proj=p1; dt=dt1; y=y1; base=32; s=1; }
  else              { b-=384; xc=xc2; proj=p2; dt=dt2; y=y2; base=48; s=2; }
  const int chunk = b >> 3;
  const int d     = (b & 7)*256 + threadIdx.x;
  const int t0    = chunk*32;
  {
    const int k = threadIdx.x*4;
    *(float4*)&sproj[k] = *(const float4*)&proj[t0*32 + k];
  }
  __syncthreads();

  float H[16];
  const float* hi = Hinit + ((size_t)(base+chunk)*2048 + d)*16;
#pragma unroll
  for (int n=0;n<16;n++) H[n] = hi[n];
  const float Dv = Dp_all[s*DIN + d];
  const float* dtp = dt + (size_t)t0*DIN + d;
  const float* xcp = xc + (size_t)t0*DIN + d;
  float* yp = y + (size_t)t0*DIN + d;
  float dtn = dtp[0], xcn = xcp[0];
  for (int tt=0; tt<32; tt++){
    const float dtv = dtn, xcv = xcn;
    if (tt < 31){ dtn = dtp[(size_t)(tt+1)*DIN]; xcn = xcp[(size_t)(tt+1)*DIN]; }
    const float e = __expf(-dtv);
    const float c = dtv*xcv;
    const float* Bp = &sproj[tt*32];
    float ep = e;
    float pacc = 0.f;
#pragma unroll
    for (int n=0;n<16;n++){
      const float dA  = fmaxf(ep, 1e-38f);
      const float dBx = fmaxf(c*Bp[n], 1e-38f);
      H[n] = dA*H[n] + dBx;
      pacc += Bp[16+n]*H[n];
      ep *= e;
    }
    yp[(size_t)tt*DIN] = pacc + Dv*xcv;
  }
}

// ---------------- upsample + fuse + ctx ----------------
__device__ __forceinline__ float ups_read(const float* __restrict__ ys, int Tin, int t, int d){
  const float scale = (float)Tin * (1.f/1024.f);
  float pos = ((float)t + 0.5f)*scale - 0.5f;
  pos = fminf(fmaxf(pos, 0.f), (float)(Tin-1));
  const int lo = (int)floorf(pos);
  const float w = pos - (float)lo;
  const int hi = min(lo+1, Tin-1);
  return ys[(size_t)lo*DIN + d]*(1.f-w) + ys[(size_t)hi*DIN + d]*w;
}

__global__ __launch_bounds__(256) void fuse_kernel(const float* __restrict__ y0,
    const float* __restrict__ y1, const float* __restrict__ y2,
    const float* __restrict__ sw, u16* __restrict__ ctxb, float* __restrict__ fused){
  const int idx = blockIdx.x*256 + threadIdx.x;
  const int t = idx >> 11, d = idx & 2047;
  const float w0r = sw[0], w1r = sw[1], w2r = sw[2];
  const float mx = fmaxf(w0r, fmaxf(w1r, w2r));
  float e0 = __expf(w0r-mx), e1 = __expf(w1r-mx), e2 = __expf(w2r-mx);
  const float inv = 1.f/(e0+e1+e2);
  e0 *= inv; e1 *= inv; e2 *= inv;
  const float o0 = y0[idx];
  const float o1 = ups_read(y1, 512, t, d);
  const float o2 = ups_read(y2, 256, t, d);
  fused[idx] = e0*o0 + e1*o1 + e2*o2;
  ctxb[idx]  = f2bf((o0+o1+o2)*(1.f/3.f));
}

// ---------------- LayerNorm ----------------
__global__ __launch_bounds__(256) void ln_kernel(const float* __restrict__ ypre,
    const float* __restrict__ g, const float* __restrict__ b, float* __restrict__ out){
  __shared__ float red[4];
  const int t = blockIdx.x;
  const float* row = ypre + (size_t)t*1024;
  float v[4];
  float s = 0.f;
#pragma unroll
  for (int i=0;i<4;i++){ v[i] = row[threadIdx.x + i*256]; s += v[i]; }
  s += __shfl_xor(s,1); s += __shfl_xor(s,2); s += __shfl_xor(s,4);
  s += __shfl_xor(s,8); s += __shfl_xor(s,16); s += __shfl_xor(s,32);
  if ((threadIdx.x & 63) == 0) red[threadIdx.x>>6] = s;
  __syncthreads();
  const float mu = (red[0]+red[1]+red[2]+red[3]) * (1.f/1024.f);
  __syncthreads();
  float q = 0.f;
#pragma unroll
  for (int i=0;i<4;i++){ const float dd = v[i]-mu; q += dd*dd; }
  q += __shfl_xor(q,1); q += __shfl_xor(q,2); q += __shfl_xor(q,4);
  q += __shfl_xor(q,8); q += __shfl_xor(q,16); q += __shfl_xor(q,32);
  if ((threadIdx.x & 63) == 0) red[threadIdx.x>>6] = q;
  __syncthreads();
  const float rstd = rsqrtf((red[0]+red[1]+red[2]+red[3]) * (1.f/1024.f) + 1e-5f);
#pragma unroll
  for (int i=0;i<4;i++){
    const int c = threadIdx.x + i*256;
    out[(size_t)t*1024 + c] = (v[i]-mu)*rstd*g[c] + b[c];
  }
}

extern "C" void kernel_launch(void* const* d_in, const int* in_sizes, int n_in,
                              void* d_out, int out_size, void* d_ws, size_t ws_size,
                              hipStream_t stream) {
  const float* x     = (const float*)d_in[0];
  const float* inpw  = (const float*)d_in[1];
  const float* convw = (const float*)d_in[2];
  const float* convb = (const float*)d_in[3];
  const float* xpw   = (const float*)d_in[4];
  const float* dtw   = (const float*)d_in[5];
  const float* dtb   = (const float*)d_in[6];
  const float* Dp    = (const float*)d_in[7];
  const float* sw    = (const float*)d_in[8];
  const float* gw1   = (const float*)d_in[9];
  const float* gw2   = (const float*)d_in[10];
  const float* opw   = (const float*)d_in[11];
  const float* lng   = (const float*)d_in[12];
  const float* lnb   = (const float*)d_in[13];
  float* out = (float*)d_out;

  char* ws = (char*)d_ws;
  u16*    wInp  = (u16*)   (ws + OFF_WINP);
  u16*    wG1   = (u16*)   (ws + OFF_WG1);
  u16*    wG2   = (u16*)   (ws + OFF_WG2);
  u16*    wOp   = (u16*)   (ws + OFF_WOP);
  u16*    xb    = (u16*)   (ws + OFF_XB);
  float*  xin   = (float*) (ws + OFF_XIN);
  float*  sgate = (float*) (ws + OFF_SGATE);
  float*  x1    = (float*) (ws + OFF_X1);
  float*  x2    = (float*) (ws + OFF_X2);
  float*  xc0   = (float*) (ws + OFF_XC0);
  float*  xc1   = (float*) (ws + OFF_XC1);
  float*  xc2   = (float*) (ws + OFF_XC2);
  float*  dt0   = (float*) (ws + OFF_DT0);
  float*  dt1   = (float*) (ws + OFF_DT1);
  float*  dt2   = (float*) (ws + OFF_DT2);
  float*  y0    = (float*) (ws + OFF_Y0);
  float*  y1    = (float*) (ws + OFF_Y1);
  float*  y2    = (float*) (ws + OFF_Y2);
  float*  p0    = (float*) (ws + OFF_P0);
  float*  p1    = (float*) (ws + OFF_P1);
  float*  p2    = (float*) (ws + OFF_P2);
  float2* PS    = (float2*)(ws + OFF_PS);
  float*  Hinit = (float*) (ws + OFF_HINIT);
  u16*    ctxb  = (u16*)   (ws + OFF_CTXB);
  u16*    t1b   = (u16*)   (ws + OFF_T1B);
  float*  fused = (float*) (ws + OFF_FUSED);
  u16*    g3o   = (u16*)   (ws + OFF_G3O);
  float*  ypre  = (float*) (ws + OFF_YPRE);

  // convert f32 -> bf16: big GEMM weights + x
  cvt_kernel<<<11264, 256, 0, stream>>>(inpw, wInp, gw1, wG1, gw2, wG2, opw, wOp, x, xb);
  // G1: xz = x @ in_proj_w^T -> x_in (f32) + downsampled x1,x2 + silu(gate) (f32)
  gemm_bt<0,128><<<dim3(32, 8), 256, 0, stream>>>(xb, wInp, 1024, 4096, 1024,
                                                  xin, sgate, nullptr, x1, x2);
  // conv + silu (all scales)
  conv_kernel<<<(1792*DIN)/256, 256, 0, stream>>>(xin, x1, x2, convw, convb, xc0, xc1, xc2);
  // xproj (block per t, LDS-staged xc row)
  xproj_kernel<<<1792, 256, 0, stream>>>(xc0, xc1, xc2, xpw, p0, p1, p2);
  // dtproj + softplus^2
  dtproj_kernel<<<(1792*DIN)/256, 256, 0, stream>>>(p0, p1, p2, dtw, dtb, dt0, dt1, dt2);
  // chunked SSM scan
  scan_p1<<<448, 256, 0, stream>>>(xc0, xc1, xc2, p0, p1, p2, dt0, dt1, dt2, PS);
  scan_combine<<<384, 256, 0, stream>>>(PS, Hinit);
  scan_p2<<<448, 256, 0, stream>>>(xc0, xc1, xc2, p0, p1, p2, dt0, dt1, dt2,
                                   Hinit, Dp, y0, y1, y2);
  // upsample + fuse + ctx
  fuse_kernel<<<(1024*DIN)/256, 256, 0, stream>>>(y0, y1, y2, sw, ctxb, fused);
  // G2: t1 = silu(ctx @ gate_w1^T)   — 64x64 tiles -> 256 blocks
  gemm_bt<1,64><<<dim3(16, 16), 256, 0, stream>>>(ctxb, wG1, 1024, 1024, 2048,
                                                  nullptr, nullptr, t1b, nullptr, nullptr);
  // G3: g3o = sigmoid(t1 @ gate_w2^T) * fused * sgate — 512 blocks
  gemm_bt<2,64><<<dim3(32, 16), 256, 0, stream>>>(t1b, wG2, 1024, 2048, 1024,
                                                  nullptr, nullptr, g3o, fused, sgate);
  // G4: ypre = g3o @ out_proj_w^T + x — 256 blocks
  gemm_bt<3,64><<<dim3(16, 16), 256, 0, stream>>>(g3o, wOp, 1024, 1024, 2048,
                                                  ypre, nullptr, nullptr, const_cast<float*>(x), nullptr);
  // LayerNorm -> f32 out
  ln_kernel<<<1024, 256, 0, stream>>>(ypre, lng, lnb, out);
}